// Round 4
// baseline (242.182 us; speedup 1.0000x reference)
//
#include <hip/hip_runtime.h>
#include <hip/hip_bf16.h>
#include <math.h>
#include <type_traits>

// Problem constants (CausalSelfAttention, GPT-2 small shape)
#define BATCH 8
#define SEQ   1024
#define NEMBD 768
#define NHEAD 12
#define HDIM  64
#define TC    (3 * NEMBD)   // 2304

typedef __attribute__((ext_vector_type(4))) float f32x4;
typedef __attribute__((ext_vector_type(8))) short s16x8;   // 8 bf16 in 4 VGPRs

__device__ __forceinline__ unsigned short f2bf(float f) {
    return __builtin_bit_cast(unsigned short, __float2bfloat16(f));
}

// async global->LDS, 16B per lane (dwordx4)
__device__ __forceinline__ void gload_lds16(const void* g, void* l) {
    __builtin_amdgcn_global_load_lds(
        (const __attribute__((address_space(1))) void*)g,
        (__attribute__((address_space(3))) void*)l, 16, 0, 0);
}

// ---------------------------------------------------------------------------
// cast fp32 -> bf16, 8 elements/thread
// ---------------------------------------------------------------------------
__global__ __launch_bounds__(256) void cast_bf16_kernel(
    const float* __restrict__ in, unsigned short* __restrict__ out, int n)
{
    const int i = (blockIdx.x * 256 + threadIdx.x) * 8;
    float4 a = *(const float4*)(in + i);
    float4 b = *(const float4*)(in + i + 4);
    s16x8 v;
    v[0] = f2bf(a.x); v[1] = f2bf(a.y); v[2] = f2bf(a.z); v[3] = f2bf(a.w);
    v[4] = f2bf(b.x); v[5] = f2bf(b.y); v[6] = f2bf(b.z); v[7] = f2bf(b.w);
    *(s16x8*)(out + i) = v;
}

// ---------------------------------------------------------------------------
// transpose + cast: w[K][N] fp32 -> wT[N][K] bf16. 32x32 LDS tiles.
// ---------------------------------------------------------------------------
__global__ __launch_bounds__(256) void transpose_cast_kernel(
    const float* __restrict__ w, unsigned short* __restrict__ wT, int K, int N)
{
    __shared__ float t[32][33];
    const int tx = threadIdx.x, ty = threadIdx.y;   // block (32,8)
    const int n0 = blockIdx.x * 32, k0 = blockIdx.y * 32;
    #pragma unroll
    for (int i = 0; i < 4; ++i)
        t[ty + i * 8][tx] = w[(size_t)(k0 + ty + i * 8) * N + n0 + tx];
    __syncthreads();
    #pragma unroll
    for (int i = 0; i < 4; ++i)
        wT[(size_t)(n0 + ty + i * 8) * K + k0 + tx] = f2bf(t[tx][ty + i * 8]);
}

// ---------------------------------------------------------------------------
// bf16 MFMA GEMM (m97 structure), fp32 output + bias:
// C[M,N] = A[M,K] @ Bt[N,K]^T + bias.  128x128 tile, BK=32, 4 waves.
// ---------------------------------------------------------------------------
__global__ __launch_bounds__(256) void gemm_mfma_f32_kernel(
    const unsigned short* __restrict__ A,
    const unsigned short* __restrict__ Bt,
    const float* __restrict__ bias,
    float* __restrict__ C,
    int M, int N, int K)
{
    __shared__ __align__(16) unsigned short As[128 * 32];
    __shared__ __align__(16) unsigned short Bs[128 * 32];

    const int tid  = threadIdx.x;
    const int w    = tid >> 6, lane = tid & 63;
    const int lr   = lane & 15, lg = lane >> 4;
    const int wr   = w >> 1, wc = w & 1;
    const int bm   = blockIdx.y * 128, bn = blockIdx.x * 128;

    const int srow = tid >> 2;
    const int sk   = (tid & 3) * 8;
    const unsigned short* Ag = A  + (size_t)(bm + srow) * K + sk;
    const unsigned short* Bg = Bt + (size_t)(bn + srow) * K + sk;
    unsigned short* Al = As + tid * 8;
    unsigned short* Bl = Bs + tid * 8;
    const size_t half = (size_t)64 * K;

    f32x4 acc[4][4];
    #pragma unroll
    for (int m = 0; m < 4; ++m)
        #pragma unroll
        for (int n = 0; n < 4; ++n) acc[m][n] = (f32x4){0.f, 0.f, 0.f, 0.f};

    for (int k0 = 0; k0 < K; k0 += 32) {
        __syncthreads();
        gload_lds16(Ag + k0,        Al);
        gload_lds16(Ag + k0 + half, Al + 2048);
        gload_lds16(Bg + k0,        Bl);
        gload_lds16(Bg + k0 + half, Bl + 2048);
        __syncthreads();

        s16x8 af[4], bfr[4];
        #pragma unroll
        for (int m = 0; m < 4; ++m)
            af[m] = *(const s16x8*)&As[(wr * 64 + m * 16 + lr) * 32 + lg * 8];
        #pragma unroll
        for (int n = 0; n < 4; ++n)
            bfr[n] = *(const s16x8*)&Bs[(wc * 64 + n * 16 + lr) * 32 + lg * 8];
        #pragma unroll
        for (int m = 0; m < 4; ++m)
            #pragma unroll
            for (int n = 0; n < 4; ++n)
                acc[m][n] = __builtin_amdgcn_mfma_f32_16x16x32_bf16(
                    af[m], bfr[n], acc[m][n], 0, 0, 0);
    }

    #pragma unroll
    for (int n = 0; n < 4; ++n) {
        const int col = bn + wc * 64 + n * 16 + lr;
        const float bv = bias[col];
        #pragma unroll
        for (int m = 0; m < 4; ++m) {
            const int row0 = bm + wr * 64 + m * 16 + lg * 4;
            #pragma unroll
            for (int r = 0; r < 4; ++r)
                C[(size_t)(row0 + r) * N + col] = acc[m][n][r] + bv;
        }
    }
}

// ---------------------------------------------------------------------------
// Same GEMM core, QKV epilogue: writes Q[b,h,t,d], K[b,h,t,d] (bf16 scalar)
// and Vt[b,h,d,t] (bf16, ushort4-packed along t).  N = 2304 fixed.
// ---------------------------------------------------------------------------
__global__ __launch_bounds__(256) void gemm_mfma_qkv_kernel(
    const unsigned short* __restrict__ A,   // xb [M][768]
    const unsigned short* __restrict__ Bt,  // waT [2304][768]
    const float* __restrict__ bias,         // b_attn [2304]
    unsigned short* __restrict__ Qb,
    unsigned short* __restrict__ Kb,
    unsigned short* __restrict__ Vtb,
    int M, int K)
{
    constexpr int N = TC;
    __shared__ __align__(16) unsigned short As[128 * 32];
    __shared__ __align__(16) unsigned short Bs[128 * 32];

    const int tid  = threadIdx.x;
    const int w    = tid >> 6, lane = tid & 63;
    const int lr   = lane & 15, lg = lane >> 4;
    const int wr   = w >> 1, wc = w & 1;
    const int bm   = blockIdx.y * 128, bn = blockIdx.x * 128;

    const int srow = tid >> 2;
    const int sk   = (tid & 3) * 8;
    const unsigned short* Ag = A  + (size_t)(bm + srow) * K + sk;
    const unsigned short* Bg = Bt + (size_t)(bn + srow) * K + sk;
    unsigned short* Al = As + tid * 8;
    unsigned short* Bl = Bs + tid * 8;
    const size_t half = (size_t)64 * K;

    f32x4 acc[4][4];
    #pragma unroll
    for (int m = 0; m < 4; ++m)
        #pragma unroll
        for (int n = 0; n < 4; ++n) acc[m][n] = (f32x4){0.f, 0.f, 0.f, 0.f};

    for (int k0 = 0; k0 < K; k0 += 32) {
        __syncthreads();
        gload_lds16(Ag + k0,        Al);
        gload_lds16(Ag + k0 + half, Al + 2048);
        gload_lds16(Bg + k0,        Bl);
        gload_lds16(Bg + k0 + half, Bl + 2048);
        __syncthreads();

        s16x8 af[4], bfr[4];
        #pragma unroll
        for (int m = 0; m < 4; ++m)
            af[m] = *(const s16x8*)&As[(wr * 64 + m * 16 + lr) * 32 + lg * 8];
        #pragma unroll
        for (int n = 0; n < 4; ++n)
            bfr[n] = *(const s16x8*)&Bs[(wc * 64 + n * 16 + lr) * 32 + lg * 8];
        #pragma unroll
        for (int m = 0; m < 4; ++m)
            #pragma unroll
            for (int n = 0; n < 4; ++n)
                acc[m][n] = __builtin_amdgcn_mfma_f32_16x16x32_bf16(
                    af[m], bfr[n], acc[m][n], 0, 0, 0);
    }

    // epilogue: region uniform per block (768 % 128 == 0)
    const int region = bn / NEMBD;          // 0=Q, 1=K, 2=V
    #pragma unroll
    for (int n = 0; n < 4; ++n) {
        const int col = bn + wc * 64 + n * 16 + lr;
        const int hd  = col - region * NEMBD;
        const int hh  = hd >> 6, d = hd & 63;
        const float bv = bias[col];
        #pragma unroll
        for (int m = 0; m < 4; ++m) {
            const int row0 = bm + wr * 64 + m * 16 + lg * 4;
            const int bb = row0 >> 10, t0 = row0 & 1023;   // no 1024-crossing
            if (region == 2) {
                ushort4 pk;
                pk.x = f2bf(acc[m][n][0] + bv);
                pk.y = f2bf(acc[m][n][1] + bv);
                pk.z = f2bf(acc[m][n][2] + bv);
                pk.w = f2bf(acc[m][n][3] + bv);
                *(ushort4*)&Vtb[(((size_t)bb * NHEAD + hh) * HDIM + d) * SEQ + t0] = pk;
            } else {
                unsigned short* dst = (region == 0) ? Qb : Kb;
                const size_t tb = ((size_t)bb * NHEAD + hh) * SEQ;
                #pragma unroll
                for (int r = 0; r < 4; ++r)
                    dst[(tb + t0 + r) * HDIM + d] = f2bf(acc[m][n][r] + bv);
            }
        }
    }
}

// ---------------------------------------------------------------------------
// Barrier-free flash attention, bf16 MFMA.
// Grid (SEQ/128, NHEAD, BATCH), block 256 = 4 INDEPENDENT waves.
// Wave w owns 32 q-rows [qt*128+w*32, +32). Per 64-key tile:
//   QK^T: Q in regs (A), K frags loaded straight from global (B). 16 MFMA.
//   online softmax (rows per lane: q = m*16+lg*4+r), P -> per-wave LDS.
//   PV as O^T = V^T * P^T: V^T frags from global (A), P^T frags = the SAME
//   contiguous LDS reads (B). 16 MFMA. acc rescale via small LDS broadcast.
// No __syncthreads anywhere; fully-masked diagonal tiles skipped by nt.
// ---------------------------------------------------------------------------
__global__ __launch_bounds__(256) void attn_mfma_kernel(
    const unsigned short* __restrict__ Qb,
    const unsigned short* __restrict__ Kb,
    const unsigned short* __restrict__ Vtb,
    unsigned short* __restrict__ y)
{
    const int qt = blockIdx.x;            // 128-row q tile
    const int h  = blockIdx.y;
    const int b  = blockIdx.z;
    const int tid  = threadIdx.x;
    const int w    = tid >> 6;
    const int lane = tid & 63;
    const int lr   = lane & 15;
    const int lg   = lane >> 4;

    __shared__ __align__(16) unsigned short Ps[4][32][72];
    __shared__ float Als[4][32];

    const size_t bh = (size_t)b * NHEAD + h;
    const unsigned short* Qg = Qb  + (bh * SEQ + qt * 128 + w * 32) * HDIM;
    const unsigned short* Kg = Kb  + bh * SEQ * HDIM;
    const unsigned short* Vg = Vtb + bh * HDIM * SEQ;

    // Q A-frags [m][kc]: row q = m*16+lr, d = kc*32+lg*8..+7
    s16x8 qf[2][2];
    #pragma unroll
    for (int m = 0; m < 2; ++m)
        #pragma unroll
        for (int kc = 0; kc < 2; ++kc)
            qf[m][kc] = *(const s16x8*)(Qg + (size_t)(m * 16 + lr) * HDIM
                                           + kc * 32 + lg * 8);

    f32x4 acc[2][4];                      // [qf][df], O^T fragments
    #pragma unroll
    for (int q2 = 0; q2 < 2; ++q2)
        #pragma unroll
        for (int df = 0; df < 4; ++df) acc[q2][df] = (f32x4){0.f, 0.f, 0.f, 0.f};
    float mrow[2][4], lrow[2][4];
    #pragma unroll
    for (int m = 0; m < 2; ++m)
        #pragma unroll
        for (int r = 0; r < 4; ++r) { mrow[m][r] = -INFINITY; lrow[m][r] = 0.f; }

    const int nt = 2 * qt + 1 + (w >> 1);   // tiles for this wave; last is masked

    for (int kt = 0; kt < nt; ++kt) {
        const unsigned short* Kt = Kg + (size_t)(kt * 64) * HDIM;

        // ---- S = Q K^T : 16 MFMA, K B-frags straight from global ----
        f32x4 sf[2][4];
        #pragma unroll
        for (int m = 0; m < 2; ++m)
            #pragma unroll
            for (int s = 0; s < 4; ++s) sf[m][s] = (f32x4){0.f, 0.f, 0.f, 0.f};
        __builtin_amdgcn_s_setprio(1);
        #pragma unroll
        for (int s = 0; s < 4; ++s) {
            const unsigned short* kr = Kt + (size_t)(s * 16 + lr) * HDIM + lg * 8;
            s16x8 b0 = *(const s16x8*)kr;
            s16x8 b1 = *(const s16x8*)(kr + 32);
            sf[0][s] = __builtin_amdgcn_mfma_f32_16x16x32_bf16(qf[0][0], b0, sf[0][s], 0, 0, 0);
            sf[0][s] = __builtin_amdgcn_mfma_f32_16x16x32_bf16(qf[0][1], b1, sf[0][s], 0, 0, 0);
            sf[1][s] = __builtin_amdgcn_mfma_f32_16x16x32_bf16(qf[1][0], b0, sf[1][s], 0, 0, 0);
            sf[1][s] = __builtin_amdgcn_mfma_f32_16x16x32_bf16(qf[1][1], b1, sf[1][s], 0, 0, 0);
        }
        __builtin_amdgcn_s_setprio(0);

        // ---- scale + causal mask (only last tile is partial) ----
        float sv[2][4][4];
        #pragma unroll
        for (int m = 0; m < 2; ++m)
            #pragma unroll
            for (int s = 0; s < 4; ++s)
                #pragma unroll
                for (int r = 0; r < 4; ++r)
                    sv[m][s][r] = sf[m][s][r] * 0.125f;
        if (kt == nt - 1) {
            const int qbase = qt * 128 + w * 32;
            #pragma unroll
            for (int m = 0; m < 2; ++m)
                #pragma unroll
                for (int s = 0; s < 4; ++s)
                    #pragma unroll
                    for (int r = 0; r < 4; ++r)
                        if (kt * 64 + s * 16 + lr > qbase + m * 16 + lg * 4 + r)
                            sv[m][s][r] = -INFINITY;
        }

        // ---- online softmax (rows q = m*16+lg*4+r, reduce over lr lanes) ----
        float al[2][4], rs[2][4];
        #pragma unroll
        for (int m = 0; m < 2; ++m)
            #pragma unroll
            for (int r = 0; r < 4; ++r) {
                float mx = fmaxf(fmaxf(sv[m][0][r], sv[m][1][r]),
                                 fmaxf(sv[m][2][r], sv[m][3][r]));
                mx = fmaxf(mx, __shfl_xor(mx, 1, 64));
                mx = fmaxf(mx, __shfl_xor(mx, 2, 64));
                mx = fmaxf(mx, __shfl_xor(mx, 4, 64));
                mx = fmaxf(mx, __shfl_xor(mx, 8, 64));
                const float mnew = fmaxf(mrow[m][r], mx);
                al[m][r] = __expf(mrow[m][r] - mnew);
                mrow[m][r] = mnew;
                rs[m][r] = 0.f;
            }
        #pragma unroll
        for (int m = 0; m < 2; ++m)
            #pragma unroll
            for (int s = 0; s < 4; ++s)
                #pragma unroll
                for (int r = 0; r < 4; ++r) {
                    const float p = __expf(sv[m][s][r] - mrow[m][r]);
                    rs[m][r] += p;
                    Ps[w][m * 16 + lg * 4 + r][s * 16 + lr] = f2bf(p);
                }
        #pragma unroll
        for (int m = 0; m < 2; ++m)
            #pragma unroll
            for (int r = 0; r < 4; ++r) {
                float t = rs[m][r];
                t += __shfl_xor(t, 1, 64);
                t += __shfl_xor(t, 2, 64);
                t += __shfl_xor(t, 4, 64);
                t += __shfl_xor(t, 8, 64);
                lrow[m][r] = lrow[m][r] * al[m][r] + t;
            }
        if (lr == 0) {
            #pragma unroll
            for (int m = 0; m < 2; ++m)
                #pragma unroll
                for (int r = 0; r < 4; ++r)
                    Als[w][m * 16 + lg * 4 + r] = al[m][r];
        }

        // ---- rescale O^T (per-lane q = qf*16+lr) ----
        float alq0 = Als[w][lr], alq1 = Als[w][16 + lr];
        #pragma unroll
        for (int df = 0; df < 4; ++df) {
            acc[0][df] *= alq0;
            acc[1][df] *= alq1;
        }

        // ---- P^T B-frags: same contiguous reads the wave just wrote ----
        s16x8 pa[2][2];
        #pragma unroll
        for (int q2 = 0; q2 < 2; ++q2)
            #pragma unroll
            for (int kc = 0; kc < 2; ++kc)
                pa[q2][kc] = *(const s16x8*)&Ps[w][q2 * 16 + lr][kc * 32 + lg * 8];

        // ---- O^T += V^T P^T : 16 MFMA, V^T A-frags straight from global ----
        const unsigned short* Vt0 = Vg + kt * 64;
        __builtin_amdgcn_s_setprio(1);
        #pragma unroll
        for (int df = 0; df < 4; ++df) {
            const unsigned short* vr = Vt0 + (size_t)(df * 16 + lr) * SEQ + lg * 8;
            s16x8 va0 = *(const s16x8*)vr;
            s16x8 va1 = *(const s16x8*)(vr + 32);
            acc[0][df] = __builtin_amdgcn_mfma_f32_16x16x32_bf16(va0, pa[0][0], acc[0][df], 0, 0, 0);
            acc[0][df] = __builtin_amdgcn_mfma_f32_16x16x32_bf16(va1, pa[0][1], acc[0][df], 0, 0, 0);
            acc[1][df] = __builtin_amdgcn_mfma_f32_16x16x32_bf16(va0, pa[1][0], acc[1][df], 0, 0, 0);
            acc[1][df] = __builtin_amdgcn_mfma_f32_16x16x32_bf16(va1, pa[1][1], acc[1][df], 0, 0, 0);
        }
        __builtin_amdgcn_s_setprio(0);
    }

    // ---- epilogue: broadcast 1/l, write y (8B packed, d-contiguous) ----
    if (lr == 0) {
        #pragma unroll
        for (int m = 0; m < 2; ++m)
            #pragma unroll
            for (int r = 0; r < 4; ++r)
                Als[w][m * 16 + lg * 4 + r] = 1.f / lrow[m][r];
    }
    float invq[2];
    invq[0] = Als[w][lr];
    invq[1] = Als[w][16 + lr];
    #pragma unroll
    for (int q2 = 0; q2 < 2; ++q2) {
        const int t = qt * 128 + w * 32 + q2 * 16 + lr;
        unsigned short* yp = y + ((size_t)(b * SEQ) + t) * NEMBD + h * HDIM;
        #pragma unroll
        for (int df = 0; df < 4; ++df) {
            ushort4 pk;
            pk.x = f2bf(acc[q2][df][0] * invq[q2]);
            pk.y = f2bf(acc[q2][df][1] * invq[q2]);
            pk.z = f2bf(acc[q2][df][2] * invq[q2]);
            pk.w = f2bf(acc[q2][df][3] * invq[q2]);
            *(ushort4*)(yp + df * 16 + lg * 4) = pk;
        }
    }
}

// ---------------------------------------------------------------------------
extern "C" void kernel_launch(void* const* d_in, const int* in_sizes, int n_in,
                              void* d_out, int out_size, void* d_ws, size_t ws_size,
                              hipStream_t stream)
{
    const float* x      = (const float*)d_in[0];
    const float* w_attn = (const float*)d_in[1];
    const float* b_attn = (const float*)d_in[2];
    const float* w_proj = (const float*)d_in[3];
    const float* b_proj = (const float*)d_in[4];
    float* out = (float*)d_out;

    const int M = BATCH * SEQ;                       // 8192
    const size_t NQKV = (size_t)M * NEMBD;           // 6.29M elements

    unsigned short* xb  = (unsigned short*)d_ws;           // [M][768]
    unsigned short* waT = xb  + NQKV;                      // [2304][768]
    unsigned short* wpT = waT + (size_t)TC * NEMBD;        // [768][768]
    unsigned short* Qb  = wpT + (size_t)NEMBD * NEMBD;     // [B][H][T][D]
    unsigned short* Kb  = Qb  + NQKV;                      // [B][H][T][D]
    unsigned short* Vtb = Kb  + NQKV;                      // [B][H][D][T]
    unsigned short* yb  = Vtb + NQKV;                      // [M][768]

    // 0) bf16 prep
    cast_bf16_kernel<<<(M * NEMBD) / 2048, 256, 0, stream>>>(x, xb, M * NEMBD);
    transpose_cast_kernel<<<dim3(TC / 32, NEMBD / 32), dim3(32, 8), 0, stream>>>(
        w_attn, waT, NEMBD, TC);
    transpose_cast_kernel<<<dim3(NEMBD / 32, NEMBD / 32), dim3(32, 8), 0, stream>>>(
        w_proj, wpT, NEMBD, NEMBD);

    // 1) fused QKV GEMM -> Q, K, V^T buffers (bf16)
    gemm_mfma_qkv_kernel<<<dim3(TC / 128, M / 128), 256, 0, stream>>>(
        xb, waT, b_attn, Qb, Kb, Vtb, M, NEMBD);

    // 2) barrier-free MFMA attention -> yb bf16 [B,T,C]
    attn_mfma_kernel<<<dim3(SEQ / 128, NHEAD, BATCH), 256, 0, stream>>>(
        Qb, Kb, Vtb, yb);

    // 3) out(fp32) = yb @ wpT^T + b_proj
    gemm_mfma_f32_kernel<<<dim3(NEMBD / 128, M / 128), 256, 0, stream>>>(
        yb, wpT, b_proj, out, M, NEMBD, NEMBD);
}

// Round 5
// 180.779 us; speedup vs baseline: 1.3397x; 1.3397x over previous
//
#include <hip/hip_runtime.h>
#include <hip/hip_bf16.h>
#include <math.h>
#include <type_traits>

// Problem constants (CausalSelfAttention, GPT-2 small shape)
#define BATCH 8
#define SEQ   1024
#define NEMBD 768
#define NHEAD 12
#define HDIM  64
#define TC    (3 * NEMBD)   // 2304

typedef __attribute__((ext_vector_type(4))) float f32x4;
typedef __attribute__((ext_vector_type(8))) short s16x8;   // 8 bf16 in 4 VGPRs

__device__ __forceinline__ unsigned short f2bf(float f) {
    return __builtin_bit_cast(unsigned short, __float2bfloat16(f));
}

// async global->LDS, 16B per lane (dwordx4)
__device__ __forceinline__ void gload_lds16(const void* g, void* l) {
    __builtin_amdgcn_global_load_lds(
        (const __attribute__((address_space(1))) void*)g,
        (__attribute__((address_space(3))) void*)l, 16, 0, 0);
}

// ---------------------------------------------------------------------------
// cast fp32 -> bf16, 8 elements/thread
// ---------------------------------------------------------------------------
__global__ __launch_bounds__(256) void cast_bf16_kernel(
    const float* __restrict__ in, unsigned short* __restrict__ out, int n)
{
    const int i = (blockIdx.x * 256 + threadIdx.x) * 8;
    float4 a = *(const float4*)(in + i);
    float4 b = *(const float4*)(in + i + 4);
    s16x8 v;
    v[0] = f2bf(a.x); v[1] = f2bf(a.y); v[2] = f2bf(a.z); v[3] = f2bf(a.w);
    v[4] = f2bf(b.x); v[5] = f2bf(b.y); v[6] = f2bf(b.z); v[7] = f2bf(b.w);
    *(s16x8*)(out + i) = v;
}

// ---------------------------------------------------------------------------
// transpose + cast: w[K][N] fp32 -> wT[N][K] bf16. 32x32 LDS tiles.
// ---------------------------------------------------------------------------
__global__ __launch_bounds__(256) void transpose_cast_kernel(
    const float* __restrict__ w, unsigned short* __restrict__ wT, int K, int N)
{
    __shared__ float t[32][33];
    const int tx = threadIdx.x, ty = threadIdx.y;   // block (32,8)
    const int n0 = blockIdx.x * 32, k0 = blockIdx.y * 32;
    #pragma unroll
    for (int i = 0; i < 4; ++i)
        t[ty + i * 8][tx] = w[(size_t)(k0 + ty + i * 8) * N + n0 + tx];
    __syncthreads();
    #pragma unroll
    for (int i = 0; i < 4; ++i)
        wT[(size_t)(n0 + ty + i * 8) * K + k0 + tx] = f2bf(t[tx][ty + i * 8]);
}

// ---------------------------------------------------------------------------
// bf16 MFMA GEMM (m97 structure), fp32 output + bias:
// C[M,N] = A[M,K] @ Bt[N,K]^T + bias.  128x128 tile, BK=32, 4 waves.
// ---------------------------------------------------------------------------
__global__ __launch_bounds__(256) void gemm_mfma_f32_kernel(
    const unsigned short* __restrict__ A,
    const unsigned short* __restrict__ Bt,
    const float* __restrict__ bias,
    float* __restrict__ C,
    int M, int N, int K)
{
    __shared__ __align__(16) unsigned short As[128 * 32];
    __shared__ __align__(16) unsigned short Bs[128 * 32];

    const int tid  = threadIdx.x;
    const int w    = tid >> 6, lane = tid & 63;
    const int lr   = lane & 15, lg = lane >> 4;
    const int wr   = w >> 1, wc = w & 1;
    const int bm   = blockIdx.y * 128, bn = blockIdx.x * 128;

    const int srow = tid >> 2;
    const int sk   = (tid & 3) * 8;
    const unsigned short* Ag = A  + (size_t)(bm + srow) * K + sk;
    const unsigned short* Bg = Bt + (size_t)(bn + srow) * K + sk;
    unsigned short* Al = As + tid * 8;
    unsigned short* Bl = Bs + tid * 8;
    const size_t half = (size_t)64 * K;

    f32x4 acc[4][4];
    #pragma unroll
    for (int m = 0; m < 4; ++m)
        #pragma unroll
        for (int n = 0; n < 4; ++n) acc[m][n] = (f32x4){0.f, 0.f, 0.f, 0.f};

    for (int k0 = 0; k0 < K; k0 += 32) {
        __syncthreads();
        gload_lds16(Ag + k0,        Al);
        gload_lds16(Ag + k0 + half, Al + 2048);
        gload_lds16(Bg + k0,        Bl);
        gload_lds16(Bg + k0 + half, Bl + 2048);
        __syncthreads();

        s16x8 af[4], bfr[4];
        #pragma unroll
        for (int m = 0; m < 4; ++m)
            af[m] = *(const s16x8*)&As[(wr * 64 + m * 16 + lr) * 32 + lg * 8];
        #pragma unroll
        for (int n = 0; n < 4; ++n)
            bfr[n] = *(const s16x8*)&Bs[(wc * 64 + n * 16 + lr) * 32 + lg * 8];
        #pragma unroll
        for (int m = 0; m < 4; ++m)
            #pragma unroll
            for (int n = 0; n < 4; ++n)
                acc[m][n] = __builtin_amdgcn_mfma_f32_16x16x32_bf16(
                    af[m], bfr[n], acc[m][n], 0, 0, 0);
    }

    #pragma unroll
    for (int n = 0; n < 4; ++n) {
        const int col = bn + wc * 64 + n * 16 + lr;
        const float bv = bias[col];
        #pragma unroll
        for (int m = 0; m < 4; ++m) {
            const int row0 = bm + wr * 64 + m * 16 + lg * 4;
            #pragma unroll
            for (int r = 0; r < 4; ++r)
                C[(size_t)(row0 + r) * N + col] = acc[m][n][r] + bv;
        }
    }
}

// ---------------------------------------------------------------------------
// Same GEMM core, QKV epilogue: writes Q[b,h,t,d], K[b,h,t,d] (bf16 scalar)
// and Vt[b,h,d,t] (bf16, ushort4-packed along t).  N = 2304 fixed.
// ---------------------------------------------------------------------------
__global__ __launch_bounds__(256) void gemm_mfma_qkv_kernel(
    const unsigned short* __restrict__ A,   // xb [M][768]
    const unsigned short* __restrict__ Bt,  // waT [2304][768]
    const float* __restrict__ bias,         // b_attn [2304]
    unsigned short* __restrict__ Qb,
    unsigned short* __restrict__ Kb,
    unsigned short* __restrict__ Vtb,
    int M, int K)
{
    constexpr int N = TC;
    __shared__ __align__(16) unsigned short As[128 * 32];
    __shared__ __align__(16) unsigned short Bs[128 * 32];

    const int tid  = threadIdx.x;
    const int w    = tid >> 6, lane = tid & 63;
    const int lr   = lane & 15, lg = lane >> 4;
    const int wr   = w >> 1, wc = w & 1;
    const int bm   = blockIdx.y * 128, bn = blockIdx.x * 128;

    const int srow = tid >> 2;
    const int sk   = (tid & 3) * 8;
    const unsigned short* Ag = A  + (size_t)(bm + srow) * K + sk;
    const unsigned short* Bg = Bt + (size_t)(bn + srow) * K + sk;
    unsigned short* Al = As + tid * 8;
    unsigned short* Bl = Bs + tid * 8;
    const size_t half = (size_t)64 * K;

    f32x4 acc[4][4];
    #pragma unroll
    for (int m = 0; m < 4; ++m)
        #pragma unroll
        for (int n = 0; n < 4; ++n) acc[m][n] = (f32x4){0.f, 0.f, 0.f, 0.f};

    for (int k0 = 0; k0 < K; k0 += 32) {
        __syncthreads();
        gload_lds16(Ag + k0,        Al);
        gload_lds16(Ag + k0 + half, Al + 2048);
        gload_lds16(Bg + k0,        Bl);
        gload_lds16(Bg + k0 + half, Bl + 2048);
        __syncthreads();

        s16x8 af[4], bfr[4];
        #pragma unroll
        for (int m = 0; m < 4; ++m)
            af[m] = *(const s16x8*)&As[(wr * 64 + m * 16 + lr) * 32 + lg * 8];
        #pragma unroll
        for (int n = 0; n < 4; ++n)
            bfr[n] = *(const s16x8*)&Bs[(wc * 64 + n * 16 + lr) * 32 + lg * 8];
        #pragma unroll
        for (int m = 0; m < 4; ++m)
            #pragma unroll
            for (int n = 0; n < 4; ++n)
                acc[m][n] = __builtin_amdgcn_mfma_f32_16x16x32_bf16(
                    af[m], bfr[n], acc[m][n], 0, 0, 0);
    }

    // epilogue: region uniform per block (768 % 128 == 0)
    const int region = bn / NEMBD;          // 0=Q, 1=K, 2=V
    #pragma unroll
    for (int n = 0; n < 4; ++n) {
        const int col = bn + wc * 64 + n * 16 + lr;
        const int hd  = col - region * NEMBD;
        const int hh  = hd >> 6, d = hd & 63;
        const float bv = bias[col];
        #pragma unroll
        for (int m = 0; m < 4; ++m) {
            const int row0 = bm + wr * 64 + m * 16 + lg * 4;
            const int bb = row0 >> 10, t0 = row0 & 1023;   // no 1024-crossing
            if (region == 2) {
                ushort4 pk;
                pk.x = f2bf(acc[m][n][0] + bv);
                pk.y = f2bf(acc[m][n][1] + bv);
                pk.z = f2bf(acc[m][n][2] + bv);
                pk.w = f2bf(acc[m][n][3] + bv);
                *(ushort4*)&Vtb[(((size_t)bb * NHEAD + hh) * HDIM + d) * SEQ + t0] = pk;
            } else {
                unsigned short* dst = (region == 0) ? Qb : Kb;
                const size_t tb = ((size_t)bb * NHEAD + hh) * SEQ;
                #pragma unroll
                for (int r = 0; r < 4; ++r)
                    dst[(tb + t0 + r) * HDIM + d] = f2bf(acc[m][n][r] + bv);
            }
        }
    }
}

// ---------------------------------------------------------------------------
// Flash attention, bf16 MFMA, LDS-staged K/V with XOR swizzle + async-stage.
// Grid (SEQ/128, NHEAD, BATCH), block 256 = 4 waves, wave w owns 32 q-rows
// [qt*128+w*32, +32). All waves iterate the same NT = 2qt+2 key tiles
// (uniform -> shared staging barriers are legal); upper waves' trailing
// fully-masked tiles produce P=0 and are harmless.
// Per 64-key tile:
//   - K tile [64][64] and V^T tile [64][64] bf16 in LDS, byte ^= (row&7)<<4
//     swizzle on both ds_write and ds_read (even bank load on ds_read_b128).
//   - T14: next tile's global->reg loads issued before compute.
//   - QK^T: 16 MFMA; online softmax (C-layout rows); P -> per-wave LDS pad-72.
//   - PV as O^T = V^T * P^T: 16 MFMA; y stored as packed ushort4.
// ---------------------------------------------------------------------------
__global__ __launch_bounds__(256) void attn_mfma_kernel(
    const unsigned short* __restrict__ Qb,
    const unsigned short* __restrict__ Kb,
    const unsigned short* __restrict__ Vtb,
    unsigned short* __restrict__ y)
{
    const int qt = gridDim.x - 1 - blockIdx.x;   // long blocks dispatch first
    const int h  = blockIdx.y;
    const int b  = blockIdx.z;
    const int tid  = threadIdx.x;
    const int w    = tid >> 6;
    const int lane = tid & 63;
    const int lr   = lane & 15;
    const int lg   = lane >> 4;

    __shared__ __align__(16) unsigned short Ks[64 * 64];    // swizzled [k][d]
    __shared__ __align__(16) unsigned short Vs[64 * 64];    // swizzled [d][t]
    __shared__ __align__(16) unsigned short Ps[4][32][72];  // per-wave P [q][k]
    __shared__ float Als[4][32];

    const size_t bh = (size_t)b * NHEAD + h;
    const unsigned short* Qg = Qb  + (bh * SEQ + qt * 128 + w * 32) * HDIM;
    const unsigned short* Kg = Kb  + bh * SEQ * HDIM;
    const unsigned short* Vg = Vtb + bh * HDIM * SEQ;

    // Q A-frags [m][kc]: row q = m*16+lr, d = kc*32+lg*8..+7
    s16x8 qf[2][2];
    #pragma unroll
    for (int m = 0; m < 2; ++m)
        #pragma unroll
        for (int kc = 0; kc < 2; ++kc)
            qf[m][kc] = *(const s16x8*)(Qg + (size_t)(m * 16 + lr) * HDIM
                                           + kc * 32 + lg * 8);

    f32x4 acc[2][4];                      // [q2][df], O^T fragments
    #pragma unroll
    for (int q2 = 0; q2 < 2; ++q2)
        #pragma unroll
        for (int df = 0; df < 4; ++df) acc[q2][df] = (f32x4){0.f, 0.f, 0.f, 0.f};
    float mrow[2][4], lrow[2][4];
    #pragma unroll
    for (int m = 0; m < 2; ++m)
        #pragma unroll
        for (int r = 0; r < 4; ++r) { mrow[m][r] = -INFINITY; lrow[m][r] = 0.f; }

    // staging maps: thread -> row tid>>2, 32B chunk (tid&3)
    const int sr = tid >> 2;
    const int sc = (tid & 3) * 16;                 // element col
    const unsigned short* Kgr = Kg + (size_t)sr * HDIM + sc;
    const unsigned short* Vgr = Vg + (size_t)sr * SEQ  + sc;
    const int swz0 = sr * 128 + ((sc * 2)      ^ ((sr & 7) << 4));
    const int swz1 = sr * 128 + ((sc * 2 + 16) ^ ((sr & 7) << 4));
    const int xorv = (lr & 7) << 4;                // read-side swizzle

    const int NT = 2 * qt + 2;
    const int qbase = qt * 128 + w * 32;

    // prologue: tile-0 loads into regs
    s16x8 krA = *(const s16x8*)(Kgr);
    s16x8 krB = *(const s16x8*)(Kgr + 8);
    s16x8 vrA = *(const s16x8*)(Vgr);
    s16x8 vrB = *(const s16x8*)(Vgr + 8);

    for (int kt = 0; kt < NT; ++kt) {
        __syncthreads();                           // LDS consumed
        *(s16x8*)((char*)Ks + swz0) = krA;
        *(s16x8*)((char*)Ks + swz1) = krB;
        *(s16x8*)((char*)Vs + swz0) = vrA;
        *(s16x8*)((char*)Vs + swz1) = vrB;
        __syncthreads();                           // tile visible
        if (kt + 1 < NT) {                         // T14: issue next loads now
            krA = *(const s16x8*)(Kgr + (size_t)(kt + 1) * 64 * HDIM);
            krB = *(const s16x8*)(Kgr + (size_t)(kt + 1) * 64 * HDIM + 8);
            vrA = *(const s16x8*)(Vgr + (kt + 1) * 64);
            vrB = *(const s16x8*)(Vgr + (kt + 1) * 64 + 8);
        }

        // ---- S = Q K^T : 16 MFMA, K B-frags from swizzled LDS ----
        f32x4 sf[2][4];
        #pragma unroll
        for (int m = 0; m < 2; ++m)
            #pragma unroll
            for (int s = 0; s < 4; ++s) sf[m][s] = (f32x4){0.f, 0.f, 0.f, 0.f};
        __builtin_amdgcn_s_setprio(1);
        #pragma unroll
        for (int s = 0; s < 4; ++s) {
            const int rb = (s * 16 + lr) * 128;
            s16x8 b0 = *(const s16x8*)((const char*)Ks + rb + ((lg * 16) ^ xorv));
            s16x8 b1 = *(const s16x8*)((const char*)Ks + rb + ((64 + lg * 16) ^ xorv));
            sf[0][s] = __builtin_amdgcn_mfma_f32_16x16x32_bf16(qf[0][0], b0, sf[0][s], 0, 0, 0);
            sf[0][s] = __builtin_amdgcn_mfma_f32_16x16x32_bf16(qf[0][1], b1, sf[0][s], 0, 0, 0);
            sf[1][s] = __builtin_amdgcn_mfma_f32_16x16x32_bf16(qf[1][0], b0, sf[1][s], 0, 0, 0);
            sf[1][s] = __builtin_amdgcn_mfma_f32_16x16x32_bf16(qf[1][1], b1, sf[1][s], 0, 0, 0);
        }
        __builtin_amdgcn_s_setprio(0);

        // ---- scale + causal mask ----
        float sv[2][4][4];
        #pragma unroll
        for (int m = 0; m < 2; ++m)
            #pragma unroll
            for (int s = 0; s < 4; ++s)
                #pragma unroll
                for (int r = 0; r < 4; ++r)
                    sv[m][s][r] = sf[m][s][r] * 0.125f;
        if (kt * 64 + 63 > qbase) {                // tile can mask this wave
            #pragma unroll
            for (int m = 0; m < 2; ++m)
                #pragma unroll
                for (int s = 0; s < 4; ++s)
                    #pragma unroll
                    for (int r = 0; r < 4; ++r)
                        if (kt * 64 + s * 16 + lr > qbase + m * 16 + lg * 4 + r)
                            sv[m][s][r] = -INFINITY;
        }

        // ---- online softmax (rows q = m*16+lg*4+r, reduce over lr lanes) ----
        float al[2][4], rs[2][4];
        #pragma unroll
        for (int m = 0; m < 2; ++m)
            #pragma unroll
            for (int r = 0; r < 4; ++r) {
                float mx = fmaxf(fmaxf(sv[m][0][r], sv[m][1][r]),
                                 fmaxf(sv[m][2][r], sv[m][3][r]));
                mx = fmaxf(mx, __shfl_xor(mx, 1, 64));
                mx = fmaxf(mx, __shfl_xor(mx, 2, 64));
                mx = fmaxf(mx, __shfl_xor(mx, 4, 64));
                mx = fmaxf(mx, __shfl_xor(mx, 8, 64));
                const float mnew = fmaxf(mrow[m][r], mx);
                al[m][r] = __expf(mrow[m][r] - mnew);
                mrow[m][r] = mnew;
                rs[m][r] = 0.f;
            }
        #pragma unroll
        for (int m = 0; m < 2; ++m)
            #pragma unroll
            for (int s = 0; s < 4; ++s)
                #pragma unroll
                for (int r = 0; r < 4; ++r) {
                    const float p = __expf(sv[m][s][r] - mrow[m][r]);
                    rs[m][r] += p;
                    Ps[w][m * 16 + lg * 4 + r][s * 16 + lr] = f2bf(p);
                }
        #pragma unroll
        for (int m = 0; m < 2; ++m)
            #pragma unroll
            for (int r = 0; r < 4; ++r) {
                float t = rs[m][r];
                t += __shfl_xor(t, 1, 64);
                t += __shfl_xor(t, 2, 64);
                t += __shfl_xor(t, 4, 64);
                t += __shfl_xor(t, 8, 64);
                lrow[m][r] = lrow[m][r] * al[m][r] + t;
            }
        if (lr == 0) {
            #pragma unroll
            for (int m = 0; m < 2; ++m)
                #pragma unroll
                for (int r = 0; r < 4; ++r)
                    Als[w][m * 16 + lg * 4 + r] = al[m][r];
        }

        // ---- rescale O^T (per-lane q = q2*16+lr) ----
        float alq0 = Als[w][lr], alq1 = Als[w][16 + lr];
        #pragma unroll
        for (int df = 0; df < 4; ++df) {
            acc[0][df] *= alq0;
            acc[1][df] *= alq1;
        }

        // ---- P^T B-frags from per-wave LDS (pad-72: even banks) ----
        s16x8 pa[2][2];
        #pragma unroll
        for (int q2 = 0; q2 < 2; ++q2)
            #pragma unroll
            for (int kc = 0; kc < 2; ++kc)
                pa[q2][kc] = *(const s16x8*)&Ps[w][q2 * 16 + lr][kc * 32 + lg * 8];

        // ---- O^T += V^T P^T : 16 MFMA, V^T A-frags from swizzled LDS ----
        __builtin_amdgcn_s_setprio(1);
        #pragma unroll
        for (int df = 0; df < 4; ++df) {
            const int rb = (df * 16 + lr) * 128;
            s16x8 va0 = *(const s16x8*)((const char*)Vs + rb + ((lg * 16) ^ xorv));
            s16x8 va1 = *(const s16x8*)((const char*)Vs + rb + ((64 + lg * 16) ^ xorv));
            acc[0][df] = __builtin_amdgcn_mfma_f32_16x16x32_bf16(va0, pa[0][0], acc[0][df], 0, 0, 0);
            acc[0][df] = __builtin_amdgcn_mfma_f32_16x16x32_bf16(va1, pa[0][1], acc[0][df], 0, 0, 0);
            acc[1][df] = __builtin_amdgcn_mfma_f32_16x16x32_bf16(va0, pa[1][0], acc[1][df], 0, 0, 0);
            acc[1][df] = __builtin_amdgcn_mfma_f32_16x16x32_bf16(va1, pa[1][1], acc[1][df], 0, 0, 0);
        }
        __builtin_amdgcn_s_setprio(0);
    }

    // ---- epilogue: broadcast 1/l, write y (8B packed, d-contiguous) ----
    if (lr == 0) {
        #pragma unroll
        for (int m = 0; m < 2; ++m)
            #pragma unroll
            for (int r = 0; r < 4; ++r)
                Als[w][m * 16 + lg * 4 + r] = 1.f / lrow[m][r];
    }
    float invq[2];
    invq[0] = Als[w][lr];
    invq[1] = Als[w][16 + lr];
    #pragma unroll
    for (int q2 = 0; q2 < 2; ++q2) {
        const int t = qt * 128 + w * 32 + q2 * 16 + lr;
        unsigned short* yp = y + ((size_t)(b * SEQ) + t) * NEMBD + h * HDIM;
        #pragma unroll
        for (int df = 0; df < 4; ++df) {
            ushort4 pk;
            pk.x = f2bf(acc[q2][df][0] * invq[q2]);
            pk.y = f2bf(acc[q2][df][1] * invq[q2]);
            pk.z = f2bf(acc[q2][df][2] * invq[q2]);
            pk.w = f2bf(acc[q2][df][3] * invq[q2]);
            *(ushort4*)(yp + df * 16 + lg * 4) = pk;
        }
    }
}

// ---------------------------------------------------------------------------
extern "C" void kernel_launch(void* const* d_in, const int* in_sizes, int n_in,
                              void* d_out, int out_size, void* d_ws, size_t ws_size,
                              hipStream_t stream)
{
    const float* x      = (const float*)d_in[0];
    const float* w_attn = (const float*)d_in[1];
    const float* b_attn = (const float*)d_in[2];
    const float* w_proj = (const float*)d_in[3];
    const float* b_proj = (const float*)d_in[4];
    float* out = (float*)d_out;

    const int M = BATCH * SEQ;                       // 8192
    const size_t NQKV = (size_t)M * NEMBD;           // 6.29M elements

    unsigned short* xb  = (unsigned short*)d_ws;           // [M][768]
    unsigned short* waT = xb  + NQKV;                      // [2304][768]
    unsigned short* wpT = waT + (size_t)TC * NEMBD;        // [768][768]
    unsigned short* Qb  = wpT + (size_t)NEMBD * NEMBD;     // [B][H][T][D]
    unsigned short* Kb  = Qb  + NQKV;                      // [B][H][T][D]
    unsigned short* Vtb = Kb  + NQKV;                      // [B][H][D][T]
    unsigned short* yb  = Vtb + NQKV;                      // [M][768]

    // 0) bf16 prep
    cast_bf16_kernel<<<(M * NEMBD) / 2048, 256, 0, stream>>>(x, xb, M * NEMBD);
    transpose_cast_kernel<<<dim3(TC / 32, NEMBD / 32), dim3(32, 8), 0, stream>>>(
        w_attn, waT, NEMBD, TC);
    transpose_cast_kernel<<<dim3(NEMBD / 32, NEMBD / 32), dim3(32, 8), 0, stream>>>(
        w_proj, wpT, NEMBD, NEMBD);

    // 1) fused QKV GEMM -> Q, K, V^T buffers (bf16)
    gemm_mfma_qkv_kernel<<<dim3(TC / 128, M / 128), 256, 0, stream>>>(
        xb, waT, b_attn, Qb, Kb, Vtb, M, NEMBD);

    // 2) LDS-staged swizzled MFMA attention -> yb bf16 [B,T,C]
    attn_mfma_kernel<<<dim3(SEQ / 128, NHEAD, BATCH), 256, 0, stream>>>(
        Qb, Kb, Vtb, yb);

    // 3) out(fp32) = yb @ wpT^T + b_proj
    gemm_mfma_f32_kernel<<<dim3(NEMBD / 128, M / 128), 256, 0, stream>>>(
        yb, wpT, b_proj, out, M, NEMBD, NEMBD);
}

// Round 6
// 134.473 us; speedup vs baseline: 1.8010x; 1.3443x over previous
//
#include <hip/hip_runtime.h>
#include <hip/hip_bf16.h>
#include <math.h>
#include <type_traits>

// Problem constants (CausalSelfAttention, GPT-2 small shape)
#define BATCH 8
#define SEQ   1024
#define NEMBD 768
#define NHEAD 12
#define HDIM  64
#define TC    (3 * NEMBD)   // 2304

typedef __attribute__((ext_vector_type(4))) float f32x4;
typedef __attribute__((ext_vector_type(8))) short s16x8;   // 8 bf16 in 4 VGPRs

__device__ __forceinline__ unsigned short f2bf(float f) {
    return __builtin_bit_cast(unsigned short, __float2bfloat16(f));
}

// async global->LDS, 16B per lane (dwordx4)
__device__ __forceinline__ void gload_lds16(const void* g, void* l) {
    __builtin_amdgcn_global_load_lds(
        (const __attribute__((address_space(1))) void*)g,
        (__attribute__((address_space(3))) void*)l, 16, 0, 0);
}

// ---------------------------------------------------------------------------
// cast fp32 -> bf16, 8 elements/thread
// ---------------------------------------------------------------------------
__global__ __launch_bounds__(256) void cast_bf16_kernel(
    const float* __restrict__ in, unsigned short* __restrict__ out, int n)
{
    const int i = (blockIdx.x * 256 + threadIdx.x) * 8;
    float4 a = *(const float4*)(in + i);
    float4 b = *(const float4*)(in + i + 4);
    s16x8 v;
    v[0] = f2bf(a.x); v[1] = f2bf(a.y); v[2] = f2bf(a.z); v[3] = f2bf(a.w);
    v[4] = f2bf(b.x); v[5] = f2bf(b.y); v[6] = f2bf(b.z); v[7] = f2bf(b.w);
    *(s16x8*)(out + i) = v;
}

// ---------------------------------------------------------------------------
// transpose + cast: w[K][N] fp32 -> wT[N][K] bf16. 32x32 LDS tiles.
// ---------------------------------------------------------------------------
__global__ __launch_bounds__(256) void transpose_cast_kernel(
    const float* __restrict__ w, unsigned short* __restrict__ wT, int K, int N)
{
    __shared__ float t[32][33];
    const int tx = threadIdx.x, ty = threadIdx.y;   // block (32,8)
    const int n0 = blockIdx.x * 32, k0 = blockIdx.y * 32;
    #pragma unroll
    for (int i = 0; i < 4; ++i)
        t[ty + i * 8][tx] = w[(size_t)(k0 + ty + i * 8) * N + n0 + tx];
    __syncthreads();
    #pragma unroll
    for (int i = 0; i < 4; ++i)
        wT[(size_t)(n0 + ty + i * 8) * K + k0 + tx] = f2bf(t[tx][ty + i * 8]);
}

// ---------------------------------------------------------------------------
// bf16 MFMA GEMM (m97 structure), fp32 output + bias:
// C[M,N] = A[M,K] @ Bt[N,K]^T + bias.  128x128 tile, BK=32, 4 waves.
// ---------------------------------------------------------------------------
__global__ __launch_bounds__(256) void gemm_mfma_f32_kernel(
    const unsigned short* __restrict__ A,
    const unsigned short* __restrict__ Bt,
    const float* __restrict__ bias,
    float* __restrict__ C,
    int M, int N, int K)
{
    __shared__ __align__(16) unsigned short As[128 * 32];
    __shared__ __align__(16) unsigned short Bs[128 * 32];

    const int tid  = threadIdx.x;
    const int w    = tid >> 6, lane = tid & 63;
    const int lr   = lane & 15, lg = lane >> 4;
    const int wr   = w >> 1, wc = w & 1;
    const int bm   = blockIdx.y * 128, bn = blockIdx.x * 128;

    const int srow = tid >> 2;
    const int sk   = (tid & 3) * 8;
    const unsigned short* Ag = A  + (size_t)(bm + srow) * K + sk;
    const unsigned short* Bg = Bt + (size_t)(bn + srow) * K + sk;
    unsigned short* Al = As + tid * 8;
    unsigned short* Bl = Bs + tid * 8;
    const size_t half = (size_t)64 * K;

    f32x4 acc[4][4];
    #pragma unroll
    for (int m = 0; m < 4; ++m)
        #pragma unroll
        for (int n = 0; n < 4; ++n) acc[m][n] = (f32x4){0.f, 0.f, 0.f, 0.f};

    for (int k0 = 0; k0 < K; k0 += 32) {
        __syncthreads();
        gload_lds16(Ag + k0,        Al);
        gload_lds16(Ag + k0 + half, Al + 2048);
        gload_lds16(Bg + k0,        Bl);
        gload_lds16(Bg + k0 + half, Bl + 2048);
        __syncthreads();

        s16x8 af[4], bfr[4];
        #pragma unroll
        for (int m = 0; m < 4; ++m)
            af[m] = *(const s16x8*)&As[(wr * 64 + m * 16 + lr) * 32 + lg * 8];
        #pragma unroll
        for (int n = 0; n < 4; ++n)
            bfr[n] = *(const s16x8*)&Bs[(wc * 64 + n * 16 + lr) * 32 + lg * 8];
        #pragma unroll
        for (int m = 0; m < 4; ++m)
            #pragma unroll
            for (int n = 0; n < 4; ++n)
                acc[m][n] = __builtin_amdgcn_mfma_f32_16x16x32_bf16(
                    af[m], bfr[n], acc[m][n], 0, 0, 0);
    }

    #pragma unroll
    for (int n = 0; n < 4; ++n) {
        const int col = bn + wc * 64 + n * 16 + lr;
        const float bv = bias[col];
        #pragma unroll
        for (int m = 0; m < 4; ++m) {
            const int row0 = bm + wr * 64 + m * 16 + lg * 4;
            #pragma unroll
            for (int r = 0; r < 4; ++r)
                C[(size_t)(row0 + r) * N + col] = acc[m][n][r] + bv;
        }
    }
}

// ---------------------------------------------------------------------------
// Same GEMM core, QKV epilogue: writes Q[b,h,t,d], K[b,h,t,d] (bf16 scalar)
// and Vt[b,h,d,t] (bf16, ushort4-packed along t).  N = 2304 fixed.
// ---------------------------------------------------------------------------
__global__ __launch_bounds__(256) void gemm_mfma_qkv_kernel(
    const unsigned short* __restrict__ A,   // xb [M][768]
    const unsigned short* __restrict__ Bt,  // waT [2304][768]
    const float* __restrict__ bias,         // b_attn [2304]
    unsigned short* __restrict__ Qb,
    unsigned short* __restrict__ Kb,
    unsigned short* __restrict__ Vtb,
    int M, int K)
{
    constexpr int N = TC;
    __shared__ __align__(16) unsigned short As[128 * 32];
    __shared__ __align__(16) unsigned short Bs[128 * 32];

    const int tid  = threadIdx.x;
    const int w    = tid >> 6, lane = tid & 63;
    const int lr   = lane & 15, lg = lane >> 4;
    const int wr   = w >> 1, wc = w & 1;
    const int bm   = blockIdx.y * 128, bn = blockIdx.x * 128;

    const int srow = tid >> 2;
    const int sk   = (tid & 3) * 8;
    const unsigned short* Ag = A  + (size_t)(bm + srow) * K + sk;
    const unsigned short* Bg = Bt + (size_t)(bn + srow) * K + sk;
    unsigned short* Al = As + tid * 8;
    unsigned short* Bl = Bs + tid * 8;
    const size_t half = (size_t)64 * K;

    f32x4 acc[4][4];
    #pragma unroll
    for (int m = 0; m < 4; ++m)
        #pragma unroll
        for (int n = 0; n < 4; ++n) acc[m][n] = (f32x4){0.f, 0.f, 0.f, 0.f};

    for (int k0 = 0; k0 < K; k0 += 32) {
        __syncthreads();
        gload_lds16(Ag + k0,        Al);
        gload_lds16(Ag + k0 + half, Al + 2048);
        gload_lds16(Bg + k0,        Bl);
        gload_lds16(Bg + k0 + half, Bl + 2048);
        __syncthreads();

        s16x8 af[4], bfr[4];
        #pragma unroll
        for (int m = 0; m < 4; ++m)
            af[m] = *(const s16x8*)&As[(wr * 64 + m * 16 + lr) * 32 + lg * 8];
        #pragma unroll
        for (int n = 0; n < 4; ++n)
            bfr[n] = *(const s16x8*)&Bs[(wc * 64 + n * 16 + lr) * 32 + lg * 8];
        #pragma unroll
        for (int m = 0; m < 4; ++m)
            #pragma unroll
            for (int n = 0; n < 4; ++n)
                acc[m][n] = __builtin_amdgcn_mfma_f32_16x16x32_bf16(
                    af[m], bfr[n], acc[m][n], 0, 0, 0);
    }

    // epilogue: region uniform per block (768 % 128 == 0)
    const int region = bn / NEMBD;          // 0=Q, 1=K, 2=V
    #pragma unroll
    for (int n = 0; n < 4; ++n) {
        const int col = bn + wc * 64 + n * 16 + lr;
        const int hd  = col - region * NEMBD;
        const int hh  = hd >> 6, d = hd & 63;
        const float bv = bias[col];
        #pragma unroll
        for (int m = 0; m < 4; ++m) {
            const int row0 = bm + wr * 64 + m * 16 + lg * 4;
            const int bb = row0 >> 10, t0 = row0 & 1023;   // no 1024-crossing
            if (region == 2) {
                ushort4 pk;
                pk.x = f2bf(acc[m][n][0] + bv);
                pk.y = f2bf(acc[m][n][1] + bv);
                pk.z = f2bf(acc[m][n][2] + bv);
                pk.w = f2bf(acc[m][n][3] + bv);
                *(ushort4*)&Vtb[(((size_t)bb * NHEAD + hh) * HDIM + d) * SEQ + t0] = pk;
            } else {
                unsigned short* dst = (region == 0) ? Qb : Kb;
                const size_t tb = ((size_t)bb * NHEAD + hh) * SEQ;
                #pragma unroll
                for (int r = 0; r < 4; ++r)
                    dst[(tb + t0 + r) * HDIM + d] = f2bf(acc[m][n][r] + bv);
            }
        }
    }
}

// ---------------------------------------------------------------------------
// Flash attention, bf16 MFMA, operand-swapped (S^T) softmax.
// 1-D grid 1536 = 8 XCD-classes x 12 bh-groups x 16 q-tiles. All 16 q-tiles
// of one (b,h) share one XCD-class -> K/V re-reads are L2 hits. qt descends
// within each class (long blocks first).
// Block 256 thr = 4 waves; wave w owns 16 q-rows [qt*64+w*16, +16).
// Per 64-key tile (NT = qt+1 tiles, no fully-masked tiles):
//   - K tile [64][64], V^T tile [64][64] in LDS, XOR-swizzled (row&7)<<4.
//   - S^T = K_frag x Q_frag: lane holds q-row (q=lr), 16 keys in-register ->
//     softmax = in-lane tree + 2 shfl rounds (xor 16,32); al, 1/l lane-local.
//   - P packed ds_write_b64 x4 -> per-wave Ps[16][72]; pa = 2x ds_read_b128.
//   - O^T += V^T P^T (A=V^T frags from swizzled LDS, B=pa). 8+8 MFMA.
// ---------------------------------------------------------------------------
__global__ __launch_bounds__(256) void attn_mfma_kernel(
    const unsigned short* __restrict__ Qb,
    const unsigned short* __restrict__ Kb,
    const unsigned short* __restrict__ Vtb,
    unsigned short* __restrict__ y)
{
    const int bid = blockIdx.x;
    const int xcd = bid & 7;
    const int grp = bid >> 3;             // 0..191
    const int qt  = 15 - (grp & 15);      // long blocks first within class
    const int bh  = xcd + 8 * (grp >> 4); // 0..95
    const int b   = bh / NHEAD, h = bh % NHEAD;

    const int tid  = threadIdx.x;
    const int w    = tid >> 6;
    const int lane = tid & 63;
    const int lr   = lane & 15;
    const int lg   = lane >> 4;

    __shared__ __align__(16) unsigned short Ks[64 * 64];    // swizzled [k][d]
    __shared__ __align__(16) unsigned short Vs[64 * 64];    // swizzled [d][t]
    __shared__ __align__(16) unsigned short Ps[4][16][72];  // per-wave P [q][k]

    const unsigned short* Qg = Qb  + ((size_t)bh * SEQ + qt * 64 + w * 16) * HDIM;
    const unsigned short* Kg = Kb  + (size_t)bh * SEQ * HDIM;
    const unsigned short* Vg = Vtb + (size_t)bh * HDIM * SEQ;

    // Q B-frags: col q = lr, kdim d = kc*32 + lg*8 + j
    s16x8 qf[2];
    #pragma unroll
    for (int kc = 0; kc < 2; ++kc)
        qf[kc] = *(const s16x8*)(Qg + (size_t)lr * HDIM + kc * 32 + lg * 8);

    f32x4 acc[4];                         // O^T frags: row d = df*16+lg*4+r, col q = lr
    #pragma unroll
    for (int df = 0; df < 4; ++df) acc[df] = (f32x4){0.f, 0.f, 0.f, 0.f};
    float mrow = -INFINITY, lrow = 0.f;

    // staging maps: thread -> row tid>>2, 16-elem chunk (tid&3)
    const int sr = tid >> 2;
    const int sc = (tid & 3) * 16;
    const unsigned short* Kgr = Kg + (size_t)sr * HDIM + sc;
    const unsigned short* Vgr = Vg + (size_t)sr * SEQ  + sc;
    const int swz0 = sr * 128 + ((sc * 2)      ^ ((sr & 7) << 4));
    const int swz1 = sr * 128 + ((sc * 2 + 16) ^ ((sr & 7) << 4));
    const int xorv = (lr & 7) << 4;       // read-side swizzle

    const int NT   = qt + 1;
    const int qrow = qt * 64 + w * 16 + lr;

    // prologue: tile-0 loads into regs
    s16x8 krA = *(const s16x8*)(Kgr);
    s16x8 krB = *(const s16x8*)(Kgr + 8);
    s16x8 vrA = *(const s16x8*)(Vgr);
    s16x8 vrB = *(const s16x8*)(Vgr + 8);

    for (int kt = 0; kt < NT; ++kt) {
        __syncthreads();                  // LDS consumed
        *(s16x8*)((char*)Ks + swz0) = krA;
        *(s16x8*)((char*)Ks + swz1) = krB;
        *(s16x8*)((char*)Vs + swz0) = vrA;
        *(s16x8*)((char*)Vs + swz1) = vrB;
        __syncthreads();                  // tile visible
        if (kt + 1 < NT) {                // T14: issue next tile's loads now
            krA = *(const s16x8*)(Kgr + (size_t)(kt + 1) * 64 * HDIM);
            krB = *(const s16x8*)(Kgr + (size_t)(kt + 1) * 64 * HDIM + 8);
            vrA = *(const s16x8*)(Vgr + (kt + 1) * 64);
            vrB = *(const s16x8*)(Vgr + (kt + 1) * 64 + 8);
        }

        // ---- S^T = K Q : 8 MFMA (A = K frags from swizzled LDS, B = Q) ----
        f32x4 sf[4];
        __builtin_amdgcn_s_setprio(1);
        #pragma unroll
        for (int s = 0; s < 4; ++s) {
            const int rb = (s * 16 + lr) * 128;
            s16x8 a0 = *(const s16x8*)((const char*)Ks + rb + ((lg * 16) ^ xorv));
            s16x8 a1 = *(const s16x8*)((const char*)Ks + rb + ((64 + lg * 16) ^ xorv));
            sf[s] = __builtin_amdgcn_mfma_f32_16x16x32_bf16(
                a0, qf[0], (f32x4){0.f, 0.f, 0.f, 0.f}, 0, 0, 0);
            sf[s] = __builtin_amdgcn_mfma_f32_16x16x32_bf16(a1, qf[1], sf[s], 0, 0, 0);
        }
        __builtin_amdgcn_s_setprio(0);

        // ---- scale + causal mask: key = kt*64+s*16+lg*4+r, q = qrow ----
        float sv[4][4];
        #pragma unroll
        for (int s = 0; s < 4; ++s)
            #pragma unroll
            for (int r = 0; r < 4; ++r)
                sv[s][r] = sf[s][r] * 0.125f;
        if (kt == NT - 1) {
            const int kbase = kt * 64;
            #pragma unroll
            for (int s = 0; s < 4; ++s)
                #pragma unroll
                for (int r = 0; r < 4; ++r)
                    if (kbase + s * 16 + lg * 4 + r > qrow)
                        sv[s][r] = -INFINITY;
        }

        // ---- online softmax: in-lane tree + 2 shfl rounds (lane bits 4,5) ----
        float mx4[4];
        #pragma unroll
        for (int s = 0; s < 4; ++s)
            mx4[s] = fmaxf(fmaxf(sv[s][0], sv[s][1]), fmaxf(sv[s][2], sv[s][3]));
        float mx = fmaxf(fmaxf(mx4[0], mx4[1]), fmaxf(mx4[2], mx4[3]));
        mx = fmaxf(mx, __shfl_xor(mx, 16, 64));
        mx = fmaxf(mx, __shfl_xor(mx, 32, 64));
        const float mnew = fmaxf(mrow, mx);
        const float al   = __expf(mrow - mnew);   // mrow=-inf first tile -> 0
        mrow = mnew;

        float rsum = 0.f;
        #pragma unroll
        for (int s = 0; s < 4; ++s) {
            float p0 = __expf(sv[s][0] - mnew);
            float p1 = __expf(sv[s][1] - mnew);
            float p2 = __expf(sv[s][2] - mnew);
            float p3 = __expf(sv[s][3] - mnew);
            rsum += (p0 + p1) + (p2 + p3);
            ushort4 pk;
            pk.x = f2bf(p0); pk.y = f2bf(p1); pk.z = f2bf(p2); pk.w = f2bf(p3);
            *(ushort4*)&Ps[w][lr][s * 16 + lg * 4] = pk;   // k-contiguous
        }
        rsum += __shfl_xor(rsum, 16, 64);
        rsum += __shfl_xor(rsum, 32, 64);
        lrow = lrow * al + rsum;

        #pragma unroll
        for (int df = 0; df < 4; ++df) acc[df] *= al;      // lane-local rescale

        asm volatile("s_waitcnt lgkmcnt(0)" ::: "memory");
        __builtin_amdgcn_sched_barrier(0);
        s16x8 pa[2];
        #pragma unroll
        for (int kc = 0; kc < 2; ++kc)
            pa[kc] = *(const s16x8*)&Ps[w][lr][kc * 32 + lg * 8];

        // ---- O^T += V^T P^T : 8 MFMA (A = V^T frags from swizzled LDS) ----
        __builtin_amdgcn_s_setprio(1);
        #pragma unroll
        for (int df = 0; df < 4; ++df) {
            const int rb = (df * 16 + lr) * 128;
            s16x8 va0 = *(const s16x8*)((const char*)Vs + rb + ((lg * 16) ^ xorv));
            s16x8 va1 = *(const s16x8*)((const char*)Vs + rb + ((64 + lg * 16) ^ xorv));
            acc[df] = __builtin_amdgcn_mfma_f32_16x16x32_bf16(va0, pa[0], acc[df], 0, 0, 0);
            acc[df] = __builtin_amdgcn_mfma_f32_16x16x32_bf16(va1, pa[1], acc[df], 0, 0, 0);
        }
        __builtin_amdgcn_s_setprio(0);
    }

    // ---- epilogue: lane-local 1/l, write y (8B packed, d-contiguous) ----
    const float inv = 1.f / lrow;
    const int t = qt * 64 + w * 16 + lr;
    unsigned short* yp = y + ((size_t)(b * SEQ) + t) * NEMBD + h * HDIM;
    #pragma unroll
    for (int df = 0; df < 4; ++df) {
        ushort4 pk;
        pk.x = f2bf(acc[df][0] * inv);
        pk.y = f2bf(acc[df][1] * inv);
        pk.z = f2bf(acc[df][2] * inv);
        pk.w = f2bf(acc[df][3] * inv);
        *(ushort4*)(yp + df * 16 + lg * 4) = pk;
    }
}

// ---------------------------------------------------------------------------
extern "C" void kernel_launch(void* const* d_in, const int* in_sizes, int n_in,
                              void* d_out, int out_size, void* d_ws, size_t ws_size,
                              hipStream_t stream)
{
    const float* x      = (const float*)d_in[0];
    const float* w_attn = (const float*)d_in[1];
    const float* b_attn = (const float*)d_in[2];
    const float* w_proj = (const float*)d_in[3];
    const float* b_proj = (const float*)d_in[4];
    float* out = (float*)d_out;

    const int M = BATCH * SEQ;                       // 8192
    const size_t NQKV = (size_t)M * NEMBD;           // 6.29M elements

    unsigned short* xb  = (unsigned short*)d_ws;           // [M][768]
    unsigned short* waT = xb  + NQKV;                      // [2304][768]
    unsigned short* wpT = waT + (size_t)TC * NEMBD;        // [768][768]
    unsigned short* Qb  = wpT + (size_t)NEMBD * NEMBD;     // [B][H][T][D]
    unsigned short* Kb  = Qb  + NQKV;                      // [B][H][T][D]
    unsigned short* Vtb = Kb  + NQKV;                      // [B][H][D][T]
    unsigned short* yb  = Vtb + NQKV;                      // [M][768]

    // 0) bf16 prep
    cast_bf16_kernel<<<(M * NEMBD) / 2048, 256, 0, stream>>>(x, xb, M * NEMBD);
    transpose_cast_kernel<<<dim3(TC / 32, NEMBD / 32), dim3(32, 8), 0, stream>>>(
        w_attn, waT, NEMBD, TC);
    transpose_cast_kernel<<<dim3(NEMBD / 32, NEMBD / 32), dim3(32, 8), 0, stream>>>(
        w_proj, wpT, NEMBD, NEMBD);

    // 1) fused QKV GEMM -> Q, K, V^T buffers (bf16)
    gemm_mfma_qkv_kernel<<<dim3(TC / 128, M / 128), 256, 0, stream>>>(
        xb, waT, b_attn, Qb, Kb, Vtb, M, NEMBD);

    // 2) operand-swapped MFMA attention -> yb bf16 [B,T,C]
    attn_mfma_kernel<<<16 * NHEAD * BATCH, 256, 0, stream>>>(Qb, Kb, Vtb, yb);

    // 3) out(fp32) = yb @ wpT^T + b_proj
    gemm_mfma_f32_kernel<<<dim3(NEMBD / 128, M / 128), 256, 0, stream>>>(
        yb, wpT, b_proj, out, M, NEMBD, NEMBD);
}